// Round 4
// baseline (650.121 us; speedup 1.0000x reference)
//
#include <hip/hip_runtime.h>
#include <hip/hip_bf16.h>
#include <math.h>

typedef __attribute__((ext_vector_type(8))) short short8;
typedef __attribute__((ext_vector_type(4))) short short4v;
typedef __attribute__((ext_vector_type(4))) float f32x4;

#define GAS __attribute__((address_space(1)))
#define LAS __attribute__((address_space(3)))

__device__ __forceinline__ LAS void* to_lds(void* p) {
    return (LAS void*)(unsigned)(uintptr_t)p;
}

constexpr int Bc = 4, Tc = 2048, Dc = 1024, Nheads = 16, Hc = 64, Fc = 4096;
constexpr int Mrows = Bc * Tc;          // 8192
constexpr float LNEPS = 1e-6f;

__device__ __forceinline__ float gelu_exact(float x) {
    return 0.5f * x * (1.0f + erff(x * 0.70710678118654752440f));
}

// ---------- fp32 [K,N] -> bf16 [N,K] transpose+convert ----------
__global__ __launch_bounds__(256) void transpose_cvt(const float* __restrict__ src,
                                                     __hip_bfloat16* __restrict__ dst,
                                                     int K, int N) {
    __shared__ float tile[32][33];
    const int n0 = blockIdx.x * 32, k0 = blockIdx.y * 32;
    const int tx = threadIdx.x & 31, ty = threadIdx.x >> 5;   // 32 x 8
    #pragma unroll
    for (int i = 0; i < 32; i += 8)
        tile[ty + i][tx] = src[(size_t)(k0 + ty + i) * N + (n0 + tx)];
    __syncthreads();
    #pragma unroll
    for (int i = 0; i < 32; i += 8)
        dst[(size_t)(n0 + ty + i) * K + (k0 + tx)] = __float2bfloat16(tile[tx][ty + i]);
}

// ---------- concat bq,bk,bv -> [3072] ----------
__global__ void concat_bias(const float* __restrict__ bq, const float* __restrict__ bk,
                            const float* __restrict__ bv, float* __restrict__ dst) {
    int i = blockIdx.x * 256 + threadIdx.x;   // 3072 total
    float v = (i < 1024) ? bq[i] : (i < 2048 ? bk[i - 1024] : bv[i - 2048]);
    dst[i] = v;
}

// ---------- LayerNorm fp32 -> bf16 ----------
__global__ __launch_bounds__(256) void ln_kernel(const float* __restrict__ x,
                                                 const float* __restrict__ gamma,
                                                 const float* __restrict__ beta,
                                                 __hip_bfloat16* __restrict__ out) {
    __shared__ float2 red[4];
    const int row = blockIdx.x, tid = threadIdx.x;
    const float* xr = x + (size_t)row * Dc;
    float4 v = ((const float4*)xr)[tid];
    float s  = v.x + v.y + v.z + v.w;
    float ss = v.x * v.x + v.y * v.y + v.z * v.z + v.w * v.w;
    #pragma unroll
    for (int o = 32; o; o >>= 1) { s += __shfl_down(s, o, 64); ss += __shfl_down(ss, o, 64); }
    if ((tid & 63) == 0) red[tid >> 6] = make_float2(s, ss);
    __syncthreads();
    float2 r0 = red[0], r1 = red[1], r2 = red[2], r3 = red[3];
    s  = r0.x + r1.x + r2.x + r3.x;
    ss = r0.y + r1.y + r2.y + r3.y;
    const float mean = s * (1.0f / Dc);
    const float var  = ss * (1.0f / Dc) - mean * mean;
    const float inv  = rsqrtf(var + LNEPS);
    float4 g  = ((const float4*)gamma)[tid];
    float4 bb = ((const float4*)beta)[tid];
    __hip_bfloat16* orow = out + (size_t)row * Dc + tid * 4;
    orow[0] = __float2bfloat16((v.x - mean) * inv * g.x + bb.x);
    orow[1] = __float2bfloat16((v.y - mean) * inv * g.y + bb.y);
    orow[2] = __float2bfloat16((v.z - mean) * inv * g.z + bb.z);
    orow[3] = __float2bfloat16((v.w - mean) * inv * g.w + bb.w);
}

// ---------- bf16 MFMA GEMM (m97 structure): C = A[M,K] * Bt[N,K]^T + bias ----------
// EPI: 0 = bias only, 1 = bias+gelu, 2 = bias+fp32-residual
template <int EPI, bool OUT_BF16>
__global__ __launch_bounds__(256) void gemm_kernel(
    const __hip_bfloat16* __restrict__ A, const __hip_bfloat16* __restrict__ Bt,
    const float* __restrict__ bias, const float* __restrict__ resid,
    void* __restrict__ Cout, int M, int N, int K) {
    __shared__ __align__(16) short As[128 * 32];
    __shared__ __align__(16) short Bs[128 * 32];
    const int tid = threadIdx.x;
    const int wave = tid >> 6, lane = tid & 63, quad = lane >> 4, l16 = lane & 15;
    const int m0 = blockIdx.x * 128, n0 = blockIdx.y * 128;
    const int wm = (wave >> 1) * 64, wn = (wave & 1) * 64;
    f32x4 acc[4][4] = {};

    const int srow = wave * 16 + (lane >> 2);
    const int scol = (lane & 3) * 8;
    const short* aSrc0 = (const short*)A  + (size_t)(m0 + srow) * K + scol;
    const short* aSrc1 = aSrc0 + (size_t)64 * K;
    const short* bSrc0 = (const short*)Bt + (size_t)(n0 + srow) * K + scol;
    const short* bSrc1 = bSrc0 + (size_t)64 * K;
    LAS void* ldsA0 = to_lds(&As[(wave * 16) * 32]);
    LAS void* ldsA1 = to_lds(&As[(64 + wave * 16) * 32]);
    LAS void* ldsB0 = to_lds(&Bs[(wave * 16) * 32]);
    LAS void* ldsB1 = to_lds(&Bs[(64 + wave * 16) * 32]);

    for (int k0 = 0; k0 < K; k0 += 32) {
        __builtin_amdgcn_global_load_lds((const GAS void*)(aSrc0 + k0), ldsA0, 16, 0, 0);
        __builtin_amdgcn_global_load_lds((const GAS void*)(aSrc1 + k0), ldsA1, 16, 0, 0);
        __builtin_amdgcn_global_load_lds((const GAS void*)(bSrc0 + k0), ldsB0, 16, 0, 0);
        __builtin_amdgcn_global_load_lds((const GAS void*)(bSrc1 + k0), ldsB1, 16, 0, 0);
        __syncthreads();
        short8 af[4], bfr[4];
        #pragma unroll
        for (int i = 0; i < 4; i++) af[i]  = *(const short8*)&As[(wm + i * 16 + l16) * 32 + quad * 8];
        #pragma unroll
        for (int i = 0; i < 4; i++) bfr[i] = *(const short8*)&Bs[(wn + i * 16 + l16) * 32 + quad * 8];
        #pragma unroll
        for (int i = 0; i < 4; i++)
            #pragma unroll
            for (int j = 0; j < 4; j++)
                acc[i][j] = __builtin_amdgcn_mfma_f32_16x16x32_bf16(af[i], bfr[j], acc[i][j], 0, 0, 0);
        __syncthreads();
    }
    #pragma unroll
    for (int i = 0; i < 4; i++) {
        #pragma unroll
        for (int j = 0; j < 4; j++) {
            const int col = n0 + wn + j * 16 + l16;
            const float bv = bias[col];
            #pragma unroll
            for (int r = 0; r < 4; r++) {
                const int row = m0 + wm + i * 16 + quad * 4 + r;
                float val = acc[i][j][r] + bv;
                if (EPI == 1) val = gelu_exact(val);
                if (EPI == 2) val += resid[(size_t)row * N + col];
                if (OUT_BF16)
                    ((__hip_bfloat16*)Cout)[(size_t)row * N + col] = __float2bfloat16(val);
                else
                    ((float*)Cout)[(size_t)row * N + col] = val;
            }
        }
    }
}

// ---------- split-K GEMM: out (pre-zeroed fp32) += A * Bt^T; slice 0 adds bias+resid ----------
__global__ __launch_bounds__(256) void gemm_splitk(
    const __hip_bfloat16* __restrict__ A, const __hip_bfloat16* __restrict__ Bt,
    const float* __restrict__ bias, const float* __restrict__ resid,
    float* __restrict__ out, int M, int N, int K, int Kslice) {
    __shared__ __align__(16) short As[128 * 32];
    __shared__ __align__(16) short Bs[128 * 32];
    const int tid = threadIdx.x;
    const int wave = tid >> 6, lane = tid & 63, quad = lane >> 4, l16 = lane & 15;
    const int m0 = blockIdx.x * 128, n0 = blockIdx.y * 128;
    const int kz = blockIdx.z;
    const int wm = (wave >> 1) * 64, wn = (wave & 1) * 64;
    f32x4 acc[4][4] = {};

    const int srow = wave * 16 + (lane >> 2);
    const int scol = (lane & 3) * 8 + kz * Kslice;
    const short* aSrc0 = (const short*)A  + (size_t)(m0 + srow) * K + scol;
    const short* aSrc1 = aSrc0 + (size_t)64 * K;
    const short* bSrc0 = (const short*)Bt + (size_t)(n0 + srow) * K + scol;
    const short* bSrc1 = bSrc0 + (size_t)64 * K;
    LAS void* ldsA0 = to_lds(&As[(wave * 16) * 32]);
    LAS void* ldsA1 = to_lds(&As[(64 + wave * 16) * 32]);
    LAS void* ldsB0 = to_lds(&Bs[(wave * 16) * 32]);
    LAS void* ldsB1 = to_lds(&Bs[(64 + wave * 16) * 32]);

    for (int k0 = 0; k0 < Kslice; k0 += 32) {
        __builtin_amdgcn_global_load_lds((const GAS void*)(aSrc0 + k0), ldsA0, 16, 0, 0);
        __builtin_amdgcn_global_load_lds((const GAS void*)(aSrc1 + k0), ldsA1, 16, 0, 0);
        __builtin_amdgcn_global_load_lds((const GAS void*)(bSrc0 + k0), ldsB0, 16, 0, 0);
        __builtin_amdgcn_global_load_lds((const GAS void*)(bSrc1 + k0), ldsB1, 16, 0, 0);
        __syncthreads();
        short8 af[4], bfr[4];
        #pragma unroll
        for (int i = 0; i < 4; i++) af[i]  = *(const short8*)&As[(wm + i * 16 + l16) * 32 + quad * 8];
        #pragma unroll
        for (int i = 0; i < 4; i++) bfr[i] = *(const short8*)&Bs[(wn + i * 16 + l16) * 32 + quad * 8];
        #pragma unroll
        for (int i = 0; i < 4; i++)
            #pragma unroll
            for (int j = 0; j < 4; j++)
                acc[i][j] = __builtin_amdgcn_mfma_f32_16x16x32_bf16(af[i], bfr[j], acc[i][j], 0, 0, 0);
        __syncthreads();
    }
    #pragma unroll
    for (int i = 0; i < 4; i++) {
        #pragma unroll
        for (int j = 0; j < 4; j++) {
            const int col = n0 + wn + j * 16 + l16;
            const float bv = (kz == 0) ? bias[col] : 0.0f;
            #pragma unroll
            for (int r = 0; r < 4; r++) {
                const int row = m0 + wm + i * 16 + quad * 4 + r;
                float val = acc[i][j][r] + bv;
                if (kz == 0) val += resid[(size_t)row * N + col];
                atomicAdd(&out[(size_t)row * N + col], val);
            }
        }
    }
}

// ---------- flash attention v3: S^T orientation, 1-exp softcap, packed P, MFMA row-sums ----------
__global__ __launch_bounds__(256, 4) void flash_attn(const __hip_bfloat16* __restrict__ qkv,
                                                     __hip_bfloat16* __restrict__ ctx) {
    constexpr int NHD = 3072;
    constexpr int LQ = 72;                  // K/V LDS row stride (shorts)
    constexpr int LP = 72;                  // P LDS row stride (shorts)
    __shared__ __align__(16) short Ks[64 * LQ];       // [s][h]
    __shared__ __align__(16) short Vt[64 * LQ];       // [h][s ^ (h&0x38)]
    __shared__ __align__(16) short Ps[4 * 32 * LP];   // per-wave [q][s]

    const int tid = threadIdx.x;
    const int wave = tid >> 6, lane = tid & 63, quad = lane >> 4, l16 = lane & 15;
    const int t0 = blockIdx.x * 128;
    const int bb = blockIdx.y >> 4, hn = blockIdx.y & 15;
    const __hip_bfloat16* Qg = qkv + ((size_t)(bb * Tc + t0)) * NHD + hn * Hc;
    const __hip_bfloat16* Kg = qkv + (size_t)bb * Tc * NHD + Dc + hn * Hc;
    const __hip_bfloat16* Vg = Kg + Dc;

    const int wm = wave * 32;
    short* Psw = Ps + wave * 32 * LP;

    // hoisted Q fragments (used as MFMA B operand: n=q, k=h)
    short8 bq[2][2];
    #pragma unroll
    for (int kt = 0; kt < 2; ++kt)
        #pragma unroll
        for (int i = 0; i < 2; ++i)
            bq[kt][i] = *(const short8*)&Qg[(size_t)(wm + i * 16 + l16) * NHD + kt * 32 + quad * 8];

    const short4v ONES4 = {0x3F80, 0x3F80, 0x3F80, 0x3F80};   // bf16 1.0
    short8 ones;
    *(short4v*)&ones = ONES4;
    *((short4v*)&ones + 1) = ONES4;

    f32x4 o_acc[2][4] = {};                 // O: q-block i (2) x h-block ht (4)
    f32x4 l_mf[2]  = {};                    // row sums per q-block

    // softcap poly: p = exp(sc*(c0 + c1*u + c2*u^2)), u = sc^2  [sc = raw QK accum]
    constexpr float C0 = 0.125f;
    constexpr float C1 = -2.60416667e-7f;
    constexpr float C2 = 6.51041667e-13f;

    for (int s0 = 0; s0 < Tc; s0 += 64) {
        __syncthreads();                    // prev iter K/V reads done
        {   // stage K [s][h] and swizzled V^T
            const int r = tid >> 3, c = (tid & 7) * 8;
            #pragma unroll
            for (int p = 0; p < 2; ++p) {
                const int s = r + p * 32;
                *(short8*)&Ks[s * LQ + c] = *(const short8*)&Kg[(size_t)(s0 + s) * NHD + c];
                short8 vv = *(const short8*)&Vg[(size_t)(s0 + s) * NHD + c];
                #pragma unroll
                for (int j = 0; j < 8; ++j)
                    Vt[(c + j) * LQ + (s ^ c)] = ((short*)&vv)[j];
            }
        }
        __syncthreads();

        // S^T = K Q^T (A = K rows -> m=s, B = Q rows -> n=q), then softcap+exp -> Ps[q][s]
        #pragma unroll
        for (int jh = 0; jh < 2; ++jh) {    // j-half: s-blocks {2jh, 2jh+1}
            f32x4 st[2][2] = {};
            #pragma unroll
            for (int kt = 0; kt < 2; ++kt) {
                short8 ak[2];
                #pragma unroll
                for (int jj = 0; jj < 2; ++jj)
                    ak[jj] = *(const short8*)&Ks[((jh * 2 + jj) * 16 + l16) * LQ + kt * 32 + quad * 8];
                #pragma unroll
                for (int jj = 0; jj < 2; ++jj)
                    #pragma unroll
                    for (int i = 0; i < 2; ++i)
                        st[jj][i] = __builtin_amdgcn_mfma_f32_16x16x32_bf16(ak[jj], bq[kt][i], st[jj][i], 0, 0, 0);
            }
            // epilogue: lane holds 4 consecutive s (quad*4+r) for q = i*16+l16
            #pragma unroll
            for (int jj = 0; jj < 2; ++jj)
                #pragma unroll
                for (int i = 0; i < 2; ++i) {
                    union { short4v v; unsigned short u[4]; } pk;
                    #pragma unroll
                    for (int r = 0; r < 4; ++r) {
                        const float sc = st[jj][i][r];
                        const float u  = sc * sc;
                        float t = sc * fmaf(fmaf(C2, u, C1), u, C0);
                        t = fminf(t, 60.0f);
                        const float p = __expf(t);
                        __hip_bfloat16 h = __float2bfloat16(p);
                        pk.u[r] = __builtin_bit_cast(unsigned short, h);
                    }
                    *(short4v*)&Psw[(i * 16 + l16) * LP + (jh * 2 + jj) * 16 + quad * 4] = pk.v;
                }
        }
        asm volatile("" ::: "memory");      // order P writes before P reads (wave-private)

        // O += P V, l += P * ones   (A = P[q][s], B = Vt)
        #pragma unroll
        for (int kt = 0; kt < 2; ++kt) {
            short8 ap[2], bv_[4];
            #pragma unroll
            for (int i = 0; i < 2; ++i)
                ap[i] = *(const short8*)&Psw[(i * 16 + l16) * LP + kt * 32 + quad * 8];
            #pragma unroll
            for (int ht = 0; ht < 4; ++ht) {
                const int swzV = ht * 16 + (l16 >> 3) * 8;
                bv_[ht] = *(const short8*)&Vt[(ht * 16 + l16) * LQ + ((kt * 32 + quad * 8) ^ swzV)];
            }
            #pragma unroll
            for (int i = 0; i < 2; ++i)
                l_mf[i] = __builtin_amdgcn_mfma_f32_16x16x32_bf16(ap[i], ones, l_mf[i], 0, 0, 0);
            #pragma unroll
            for (int i = 0; i < 2; ++i)
                #pragma unroll
                for (int ht = 0; ht < 4; ++ht)
                    o_acc[i][ht] = __builtin_amdgcn_mfma_f32_16x16x32_bf16(ap[i], bv_[ht], o_acc[i][ht], 0, 0, 0);
        }
        asm volatile("" ::: "memory");      // order P reads before next iter's writes
    }

    // normalize + store (l_mf rows align with o_acc rows; no cross-lane reduce needed)
    #pragma unroll
    for (int i = 0; i < 2; ++i) {
        float linv[4];
        #pragma unroll
        for (int r = 0; r < 4; ++r) linv[r] = 1.0f / l_mf[i][r];
        #pragma unroll
        for (int ht = 0; ht < 4; ++ht)
            #pragma unroll
            for (int r = 0; r < 4; ++r) {
                const int row = t0 + wm + i * 16 + quad * 4 + r;
                const int col = hn * Hc + ht * 16 + l16;
                ctx[((size_t)(bb * Tc + row)) * Dc + col] =
                    __float2bfloat16(o_acc[i][ht][r] * linv[r]);
            }
    }
}

extern "C" void kernel_launch(void* const* d_in, const int* in_sizes, int n_in,
                              void* d_out, int out_size, void* d_ws, size_t ws_size,
                              hipStream_t stream) {
    const float* inputs = (const float*)d_in[0];
    const float* ln1_g  = (const float*)d_in[1];
    const float* ln1_b  = (const float*)d_in[2];
    const float* wq     = (const float*)d_in[3];
    const float* bq     = (const float*)d_in[4];
    const float* wk     = (const float*)d_in[5];
    const float* bk     = (const float*)d_in[6];
    const float* wv     = (const float*)d_in[7];
    const float* bv     = (const float*)d_in[8];
    const float* wo     = (const float*)d_in[9];
    const float* bo     = (const float*)d_in[10];
    const float* ln2_g  = (const float*)d_in[11];
    const float* ln2_b  = (const float*)d_in[12];
    const float* w1     = (const float*)d_in[13];
    const float* b1     = (const float*)d_in[14];
    const float* w2     = (const float*)d_in[15];
    const float* b2     = (const float*)d_in[16];

    char* ws = (char*)d_ws;
    auto alloc = [&](size_t bytes) {
        char* p = ws;
        ws += (bytes + 255) & ~(size_t)255;
        return p;
    };
    __hip_bfloat16* wqkv_t = (__hip_bfloat16*)alloc((size_t)3072 * 1024 * 2);
    __hip_bfloat16* wo_t   = (__hip_bfloat16*)alloc((size_t)1024 * 1024 * 2);
    __hip_bfloat16* w1_t   = (__hip_bfloat16*)alloc((size_t)4096 * 1024 * 2);
    __hip_bfloat16* w2_t   = (__hip_bfloat16*)alloc((size_t)4096 * 1024 * 2);
    float*          bqkv   = (float*)alloc(3072 * 4);
    __hip_bfloat16* xn     = (__hip_bfloat16*)alloc((size_t)Mrows * 1024 * 2);
    __hip_bfloat16* qkv    = (__hip_bfloat16*)alloc((size_t)Mrows * 3072 * 2);
    __hip_bfloat16* ctx    = (__hip_bfloat16*)alloc((size_t)Mrows * 1024 * 2);
    float*          xres   = (float*)alloc((size_t)Mrows * 1024 * 4);
    __hip_bfloat16* y1     = qkv;   // alias: qkv dead after attention+out-proj

    dim3 blk(256);
    transpose_cvt<<<dim3(32, 32), blk, 0, stream>>>(wq, wqkv_t, 1024, 1024);
    transpose_cvt<<<dim3(32, 32), blk, 0, stream>>>(wk, wqkv_t + 1024 * 1024, 1024, 1024);
    transpose_cvt<<<dim3(32, 32), blk, 0, stream>>>(wv, wqkv_t + 2048 * 1024, 1024, 1024);
    transpose_cvt<<<dim3(32, 32), blk, 0, stream>>>(wo, wo_t, 1024, 1024);
    transpose_cvt<<<dim3(128, 32), blk, 0, stream>>>(w1, w1_t, 1024, 4096);
    transpose_cvt<<<dim3(32, 128), blk, 0, stream>>>(w2, w2_t, 4096, 1024);
    concat_bias<<<dim3(12), blk, 0, stream>>>(bq, bk, bv, bqkv);

    ln_kernel<<<dim3(Mrows), blk, 0, stream>>>(inputs, ln1_g, ln1_b, xn);
    gemm_kernel<0, true><<<dim3(64, 24), blk, 0, stream>>>(xn, wqkv_t, bqkv, nullptr, qkv, Mrows, 3072, 1024);
    flash_attn<<<dim3(Tc / 128, Bc * Nheads), blk, 0, stream>>>(qkv, ctx);
    gemm_kernel<2, false><<<dim3(64, 8), blk, 0, stream>>>(ctx, wo_t, bo, inputs, xres, Mrows, 1024, 1024);
    ln_kernel<<<dim3(Mrows), blk, 0, stream>>>(xres, ln2_g, ln2_b, xn);
    gemm_kernel<1, true><<<dim3(64, 32), blk, 0, stream>>>(xn, w1_t, b1, nullptr, y1, Mrows, 4096, 1024);
    // out = y1 @ w2 + b2 + xres via split-K=2 (zero-init + atomic accumulate)
    hipMemsetAsync(d_out, 0, (size_t)out_size * sizeof(float), stream);
    gemm_splitk<<<dim3(64, 8, 2), blk, 0, stream>>>(y1, w2_t, b2, xres, (float*)d_out, Mrows, 1024, 4096, 2048);
}

// Round 5
// 608.006 us; speedup vs baseline: 1.0693x; 1.0693x over previous
//
#include <hip/hip_runtime.h>
#include <hip/hip_bf16.h>
#include <math.h>

typedef __attribute__((ext_vector_type(8))) short short8;
typedef __attribute__((ext_vector_type(4))) short short4v;
typedef __attribute__((ext_vector_type(4))) float f32x4;

#define GAS __attribute__((address_space(1)))
#define LAS __attribute__((address_space(3)))

__device__ __forceinline__ LAS void* to_lds(void* p) {
    return (LAS void*)(unsigned)(uintptr_t)p;
}

constexpr int Bc = 4, Tc = 2048, Dc = 1024, Nheads = 16, Hc = 64, Fc = 4096;
constexpr int Mrows = Bc * Tc;          // 8192
constexpr float LNEPS = 1e-6f;

__device__ __forceinline__ float gelu_exact(float x) {
    return 0.5f * x * (1.0f + erff(x * 0.70710678118654752440f));
}

// ---------- fp32 [K,N] -> bf16 [N,K] transpose+convert ----------
__global__ __launch_bounds__(256) void transpose_cvt(const float* __restrict__ src,
                                                     __hip_bfloat16* __restrict__ dst,
                                                     int K, int N) {
    __shared__ float tile[32][33];
    const int n0 = blockIdx.x * 32, k0 = blockIdx.y * 32;
    const int tx = threadIdx.x & 31, ty = threadIdx.x >> 5;   // 32 x 8
    #pragma unroll
    for (int i = 0; i < 32; i += 8)
        tile[ty + i][tx] = src[(size_t)(k0 + ty + i) * N + (n0 + tx)];
    __syncthreads();
    #pragma unroll
    for (int i = 0; i < 32; i += 8)
        dst[(size_t)(n0 + ty + i) * K + (k0 + tx)] = __float2bfloat16(tile[tx][ty + i]);
}

// ---------- V pre-transpose: qkv V-slice [t][h] -> vT[b][n][h][t] (bf16) ----------
__global__ __launch_bounds__(256) void transpose_v(const __hip_bfloat16* __restrict__ qkv,
                                                   __hip_bfloat16* __restrict__ vT) {
    __shared__ short tile[32][33];
    const int t0 = blockIdx.x * 32, h0 = blockIdx.y * 32, bn = blockIdx.z;
    const int b = bn >> 4, n = bn & 15;
    const short* src = (const short*)qkv + (size_t)b * Tc * 3072 + 2048 + n * 64;
    short* dst = (short*)vT + (size_t)bn * 64 * Tc;
    const int tx = threadIdx.x & 31, ty = threadIdx.x >> 5;
    #pragma unroll
    for (int i = 0; i < 32; i += 8)
        tile[ty + i][tx] = src[(size_t)(t0 + ty + i) * 3072 + h0 + tx];
    __syncthreads();
    #pragma unroll
    for (int i = 0; i < 32; i += 8)
        dst[(size_t)(h0 + ty + i) * Tc + t0 + tx] = tile[tx][ty + i];
}

// ---------- concat bq,bk,bv -> [3072] ----------
__global__ void concat_bias(const float* __restrict__ bq, const float* __restrict__ bk,
                            const float* __restrict__ bv, float* __restrict__ dst) {
    int i = blockIdx.x * 256 + threadIdx.x;   // 3072 total
    float v = (i < 1024) ? bq[i] : (i < 2048 ? bk[i - 1024] : bv[i - 2048]);
    dst[i] = v;
}

// ---------- LayerNorm fp32 -> bf16 ----------
__global__ __launch_bounds__(256) void ln_kernel(const float* __restrict__ x,
                                                 const float* __restrict__ gamma,
                                                 const float* __restrict__ beta,
                                                 __hip_bfloat16* __restrict__ out) {
    __shared__ float2 red[4];
    const int row = blockIdx.x, tid = threadIdx.x;
    const float* xr = x + (size_t)row * Dc;
    float4 v = ((const float4*)xr)[tid];
    float s  = v.x + v.y + v.z + v.w;
    float ss = v.x * v.x + v.y * v.y + v.z * v.z + v.w * v.w;
    #pragma unroll
    for (int o = 32; o; o >>= 1) { s += __shfl_down(s, o, 64); ss += __shfl_down(ss, o, 64); }
    if ((tid & 63) == 0) red[tid >> 6] = make_float2(s, ss);
    __syncthreads();
    float2 r0 = red[0], r1 = red[1], r2 = red[2], r3 = red[3];
    s  = r0.x + r1.x + r2.x + r3.x;
    ss = r0.y + r1.y + r2.y + r3.y;
    const float mean = s * (1.0f / Dc);
    const float var  = ss * (1.0f / Dc) - mean * mean;
    const float inv  = rsqrtf(var + LNEPS);
    float4 g  = ((const float4*)gamma)[tid];
    float4 bb = ((const float4*)beta)[tid];
    __hip_bfloat16* orow = out + (size_t)row * Dc + tid * 4;
    orow[0] = __float2bfloat16((v.x - mean) * inv * g.x + bb.x);
    orow[1] = __float2bfloat16((v.y - mean) * inv * g.y + bb.y);
    orow[2] = __float2bfloat16((v.z - mean) * inv * g.z + bb.z);
    orow[3] = __float2bfloat16((v.w - mean) * inv * g.w + bb.w);
}

// ---------- bf16 MFMA GEMM (m97 structure): C = A[M,K] * Bt[N,K]^T + bias ----------
// EPI: 0 = bias only, 1 = bias+gelu, 2 = bias+fp32-residual
template <int EPI, bool OUT_BF16>
__global__ __launch_bounds__(256) void gemm_kernel(
    const __hip_bfloat16* __restrict__ A, const __hip_bfloat16* __restrict__ Bt,
    const float* __restrict__ bias, const float* __restrict__ resid,
    void* __restrict__ Cout, int M, int N, int K) {
    __shared__ __align__(16) short As[128 * 32];
    __shared__ __align__(16) short Bs[128 * 32];
    const int tid = threadIdx.x;
    const int wave = tid >> 6, lane = tid & 63, quad = lane >> 4, l16 = lane & 15;
    const int m0 = blockIdx.x * 128, n0 = blockIdx.y * 128;
    const int wm = (wave >> 1) * 64, wn = (wave & 1) * 64;
    f32x4 acc[4][4] = {};

    const int srow = wave * 16 + (lane >> 2);
    const int scol = (lane & 3) * 8;
    const short* aSrc0 = (const short*)A  + (size_t)(m0 + srow) * K + scol;
    const short* aSrc1 = aSrc0 + (size_t)64 * K;
    const short* bSrc0 = (const short*)Bt + (size_t)(n0 + srow) * K + scol;
    const short* bSrc1 = bSrc0 + (size_t)64 * K;
    LAS void* ldsA0 = to_lds(&As[(wave * 16) * 32]);
    LAS void* ldsA1 = to_lds(&As[(64 + wave * 16) * 32]);
    LAS void* ldsB0 = to_lds(&Bs[(wave * 16) * 32]);
    LAS void* ldsB1 = to_lds(&Bs[(64 + wave * 16) * 32]);

    for (int k0 = 0; k0 < K; k0 += 32) {
        __builtin_amdgcn_global_load_lds((const GAS void*)(aSrc0 + k0), ldsA0, 16, 0, 0);
        __builtin_amdgcn_global_load_lds((const GAS void*)(aSrc1 + k0), ldsA1, 16, 0, 0);
        __builtin_amdgcn_global_load_lds((const GAS void*)(bSrc0 + k0), ldsB0, 16, 0, 0);
        __builtin_amdgcn_global_load_lds((const GAS void*)(bSrc1 + k0), ldsB1, 16, 0, 0);
        __syncthreads();
        short8 af[4], bfr[4];
        #pragma unroll
        for (int i = 0; i < 4; i++) af[i]  = *(const short8*)&As[(wm + i * 16 + l16) * 32 + quad * 8];
        #pragma unroll
        for (int i = 0; i < 4; i++) bfr[i] = *(const short8*)&Bs[(wn + i * 16 + l16) * 32 + quad * 8];
        #pragma unroll
        for (int i = 0; i < 4; i++)
            #pragma unroll
            for (int j = 0; j < 4; j++)
                acc[i][j] = __builtin_amdgcn_mfma_f32_16x16x32_bf16(af[i], bfr[j], acc[i][j], 0, 0, 0);
        __syncthreads();
    }
    #pragma unroll
    for (int i = 0; i < 4; i++) {
        #pragma unroll
        for (int j = 0; j < 4; j++) {
            const int col = n0 + wn + j * 16 + l16;
            const float bv = bias[col];
            #pragma unroll
            for (int r = 0; r < 4; r++) {
                const int row = m0 + wm + i * 16 + quad * 4 + r;
                float val = acc[i][j][r] + bv;
                if (EPI == 1) val = gelu_exact(val);
                if (EPI == 2) val += resid[(size_t)row * N + col];
                if (OUT_BF16)
                    ((__hip_bfloat16*)Cout)[(size_t)row * N + col] = __float2bfloat16(val);
                else
                    ((float*)Cout)[(size_t)row * N + col] = val;
            }
        }
    }
}

// ---------- flash attention v4: S^T orientation, 1-exp softcap, pre-transposed V ----------
__global__ __launch_bounds__(256, 4) void flash_attn(const __hip_bfloat16* __restrict__ qkv,
                                                     const __hip_bfloat16* __restrict__ vT,
                                                     __hip_bfloat16* __restrict__ ctx) {
    constexpr int NHD = 3072;
    constexpr int LQ = 72;                  // K/V LDS row stride (shorts)
    constexpr int LP = 72;                  // P LDS row stride (shorts)
    __shared__ __align__(16) short Ks[64 * LQ];       // [s][h]
    __shared__ __align__(16) short Vt[64 * LQ];       // [h][s]
    __shared__ __align__(16) short Ps[4 * 32 * LP];   // per-wave [q][s]

    const int tid = threadIdx.x;
    const int wave = tid >> 6, lane = tid & 63, quad = lane >> 4, l16 = lane & 15;
    const int t0 = blockIdx.x * 128;
    const int bn = blockIdx.y;
    const int bb = bn >> 4, hn = bn & 15;
    const __hip_bfloat16* Qg  = qkv + ((size_t)(bb * Tc + t0)) * NHD + hn * Hc;
    const __hip_bfloat16* Kg  = qkv + (size_t)bb * Tc * NHD + Dc + hn * Hc;
    const __hip_bfloat16* vTg = vT + (size_t)bn * 64 * Tc;

    const int wm = wave * 32;
    short* Psw = Ps + wave * 32 * LP;

    // hoisted Q fragments (used as MFMA B operand: n=q, k=h)
    short8 bq[2][2];
    #pragma unroll
    for (int kt = 0; kt < 2; ++kt)
        #pragma unroll
        for (int i = 0; i < 2; ++i)
            bq[kt][i] = *(const short8*)&Qg[(size_t)(wm + i * 16 + l16) * NHD + kt * 32 + quad * 8];

    const short4v ONES4 = {0x3F80, 0x3F80, 0x3F80, 0x3F80};   // bf16 1.0
    short8 ones;
    *(short4v*)&ones = ONES4;
    *((short4v*)&ones + 1) = ONES4;

    f32x4 o_acc[2][4] = {};                 // O: q-block i (2) x h-block ht (4)
    f32x4 l_mf[2]  = {};                    // row sums per q-block

    // softcap poly: p = exp(sc*(c0 + c1*u + c2*u^2)), u = sc^2  [sc = raw QK accum]
    constexpr float C0 = 0.125f;
    constexpr float C1 = -2.60416667e-7f;
    constexpr float C2 = 6.51041667e-13f;

    for (int s0 = 0; s0 < Tc; s0 += 64) {
        __syncthreads();                    // prev iter K/V reads done
        {   // stage K [s][h] and V^T [h][s] (both b128 writes, no scatter)
            const int r = tid >> 3, c = (tid & 7) * 8;
            #pragma unroll
            for (int p = 0; p < 2; ++p) {
                const int s = r + p * 32;
                *(short8*)&Ks[s * LQ + c] = *(const short8*)&Kg[(size_t)(s0 + s) * NHD + c];
                *(short8*)&Vt[s * LQ + c] = *(const short8*)&vTg[(size_t)s * Tc + s0 + c];
            }
        }
        __syncthreads();

        // S^T = K Q^T (A = K rows -> m=s, B = Q rows -> n=q), then softcap+exp -> Ps[q][s]
        #pragma unroll
        for (int jh = 0; jh < 2; ++jh) {    // j-half: s-blocks {2jh, 2jh+1}
            f32x4 st[2][2] = {};
            #pragma unroll
            for (int kt = 0; kt < 2; ++kt) {
                short8 ak[2];
                #pragma unroll
                for (int jj = 0; jj < 2; ++jj)
                    ak[jj] = *(const short8*)&Ks[((jh * 2 + jj) * 16 + l16) * LQ + kt * 32 + quad * 8];
                #pragma unroll
                for (int jj = 0; jj < 2; ++jj)
                    #pragma unroll
                    for (int i = 0; i < 2; ++i)
                        st[jj][i] = __builtin_amdgcn_mfma_f32_16x16x32_bf16(ak[jj], bq[kt][i], st[jj][i], 0, 0, 0);
            }
            // epilogue: lane holds 4 consecutive s (quad*4+r) for q = i*16+l16
            #pragma unroll
            for (int jj = 0; jj < 2; ++jj)
                #pragma unroll
                for (int i = 0; i < 2; ++i) {
                    union { short4v v; unsigned short u[4]; } pk;
                    #pragma unroll
                    for (int r = 0; r < 4; ++r) {
                        const float sc = st[jj][i][r];
                        const float u  = sc * sc;
                        float t = sc * fmaf(fmaf(C2, u, C1), u, C0);
                        t = fminf(t, 60.0f);
                        const float p = __expf(t);
                        __hip_bfloat16 h = __float2bfloat16(p);
                        pk.u[r] = __builtin_bit_cast(unsigned short, h);
                    }
                    *(short4v*)&Psw[(i * 16 + l16) * LP + (jh * 2 + jj) * 16 + quad * 4] = pk.v;
                }
        }
        asm volatile("" ::: "memory");      // order P writes before P reads (wave-private)

        // O += P V, l += P * ones   (A = P[q][s], B = Vt[h][s])
        #pragma unroll
        for (int kt = 0; kt < 2; ++kt) {
            short8 ap[2], bv_[4];
            #pragma unroll
            for (int i = 0; i < 2; ++i)
                ap[i] = *(const short8*)&Psw[(i * 16 + l16) * LP + kt * 32 + quad * 8];
            #pragma unroll
            for (int ht = 0; ht < 4; ++ht)
                bv_[ht] = *(const short8*)&Vt[(ht * 16 + l16) * LQ + kt * 32 + quad * 8];
            #pragma unroll
            for (int i = 0; i < 2; ++i)
                l_mf[i] = __builtin_amdgcn_mfma_f32_16x16x32_bf16(ap[i], ones, l_mf[i], 0, 0, 0);
            #pragma unroll
            for (int i = 0; i < 2; ++i)
                #pragma unroll
                for (int ht = 0; ht < 4; ++ht)
                    o_acc[i][ht] = __builtin_amdgcn_mfma_f32_16x16x32_bf16(ap[i], bv_[ht], o_acc[i][ht], 0, 0, 0);
        }
        asm volatile("" ::: "memory");      // order P reads before next iter's writes
    }

    // normalize + store (l_mf rows align with o_acc rows; no cross-lane reduce needed)
    #pragma unroll
    for (int i = 0; i < 2; ++i) {
        float linv[4];
        #pragma unroll
        for (int r = 0; r < 4; ++r) linv[r] = 1.0f / l_mf[i][r];
        #pragma unroll
        for (int ht = 0; ht < 4; ++ht)
            #pragma unroll
            for (int r = 0; r < 4; ++r) {
                const int row = t0 + wm + i * 16 + quad * 4 + r;
                const int col = hn * Hc + ht * 16 + l16;
                ctx[((size_t)(bb * Tc + row)) * Dc + col] =
                    __float2bfloat16(o_acc[i][ht][r] * linv[r]);
            }
    }
}

extern "C" void kernel_launch(void* const* d_in, const int* in_sizes, int n_in,
                              void* d_out, int out_size, void* d_ws, size_t ws_size,
                              hipStream_t stream) {
    const float* inputs = (const float*)d_in[0];
    const float* ln1_g  = (const float*)d_in[1];
    const float* ln1_b  = (const float*)d_in[2];
    const float* wq     = (const float*)d_in[3];
    const float* bq     = (const float*)d_in[4];
    const float* wk     = (const float*)d_in[5];
    const float* bk     = (const float*)d_in[6];
    const float* wv     = (const float*)d_in[7];
    const float* bv     = (const float*)d_in[8];
    const float* wo     = (const float*)d_in[9];
    const float* bo     = (const float*)d_in[10];
    const float* ln2_g  = (const float*)d_in[11];
    const float* ln2_b  = (const float*)d_in[12];
    const float* w1     = (const float*)d_in[13];
    const float* b1     = (const float*)d_in[14];
    const float* w2     = (const float*)d_in[15];
    const float* b2     = (const float*)d_in[16];

    char* ws = (char*)d_ws;
    auto alloc = [&](size_t bytes) {
        char* p = ws;
        ws += (bytes + 255) & ~(size_t)255;
        return p;
    };
    __hip_bfloat16* wqkv_t = (__hip_bfloat16*)alloc((size_t)3072 * 1024 * 2);
    __hip_bfloat16* wo_t   = (__hip_bfloat16*)alloc((size_t)1024 * 1024 * 2);
    __hip_bfloat16* w1_t   = (__hip_bfloat16*)alloc((size_t)4096 * 1024 * 2);
    __hip_bfloat16* w2_t   = (__hip_bfloat16*)alloc((size_t)4096 * 1024 * 2);
    float*          bqkv   = (float*)alloc(3072 * 4);
    __hip_bfloat16* xn     = (__hip_bfloat16*)alloc((size_t)Mrows * 1024 * 2);
    __hip_bfloat16* qkv    = (__hip_bfloat16*)alloc((size_t)Mrows * 3072 * 2);
    __hip_bfloat16* vTr    = (__hip_bfloat16*)alloc((size_t)64 * 64 * Tc * 2);
    __hip_bfloat16* ctx    = (__hip_bfloat16*)alloc((size_t)Mrows * 1024 * 2);
    float*          xres   = (float*)alloc((size_t)Mrows * 1024 * 4);
    __hip_bfloat16* y1     = qkv;   // alias: qkv dead after attention+out-proj

    dim3 blk(256);
    transpose_cvt<<<dim3(32, 32), blk, 0, stream>>>(wq, wqkv_t, 1024, 1024);
    transpose_cvt<<<dim3(32, 32), blk, 0, stream>>>(wk, wqkv_t + 1024 * 1024, 1024, 1024);
    transpose_cvt<<<dim3(32, 32), blk, 0, stream>>>(wv, wqkv_t + 2048 * 1024, 1024, 1024);
    transpose_cvt<<<dim3(32, 32), blk, 0, stream>>>(wo, wo_t, 1024, 1024);
    transpose_cvt<<<dim3(128, 32), blk, 0, stream>>>(w1, w1_t, 1024, 4096);
    transpose_cvt<<<dim3(32, 128), blk, 0, stream>>>(w2, w2_t, 4096, 1024);
    concat_bias<<<dim3(12), blk, 0, stream>>>(bq, bk, bv, bqkv);

    ln_kernel<<<dim3(Mrows), blk, 0, stream>>>(inputs, ln1_g, ln1_b, xn);
    gemm_kernel<0, true><<<dim3(64, 24), blk, 0, stream>>>(xn, wqkv_t, bqkv, nullptr, qkv, Mrows, 3072, 1024);
    transpose_v<<<dim3(64, 2, 64), blk, 0, stream>>>(qkv, vTr);
    flash_attn<<<dim3(Tc / 128, Bc * Nheads), blk, 0, stream>>>(qkv, vTr, ctx);
    gemm_kernel<2, false><<<dim3(64, 8), blk, 0, stream>>>(ctx, wo_t, bo, inputs, xres, Mrows, 1024, 1024);
    ln_kernel<<<dim3(Mrows), blk, 0, stream>>>(xres, ln2_g, ln2_b, xn);
    gemm_kernel<1, true><<<dim3(64, 32), blk, 0, stream>>>(xn, w1_t, b1, nullptr, y1, Mrows, 4096, 1024);
    gemm_kernel<2, false><<<dim3(64, 8), blk, 0, stream>>>(y1, w2_t, b2, xres, (float*)d_out, Mrows, 1024, 4096);
}